// Round 4
// baseline (532.835 us; speedup 1.0000x reference)
//
#include <hip/hip_runtime.h>

// LIF spike scan: x[N, T=32] fp32, scan over contiguous T axis.
//   u = 0.25*u*(1-o_prev) + x_t ;  o = (u > 0.5) ? 1 : 0
// 0.25*u exact (pow2), (1-o) in {0,1} exact -> bit-exact vs numpy fp32 ref.
//
// R4 = R3 with native ext_vector_type (nontemporal builtin rejects HIP float4).
//  - 4 rows/thread, loads for row k+1 issued before scanning row k.
//  - no LDS / no barriers (R2 showed coalescing was not the limiter).
//  - nontemporal stores: output is write-once; keep L2/L3 for the input.
//  - XCD-contiguous block swizzle: each XCD streams a dense slab.

typedef float fx4 __attribute__((ext_vector_type(4)));

constexpr int T = 32;
constexpr float TAU = 0.25f;
constexpr float VTH = 0.5f;
constexpr int QPR = T / 4;                    // 8 fx4 per row
constexpr int RPT = 4;                        // rows per thread
constexpr int BLOCK = 256;
constexpr int ROWS_PER_BLOCK = BLOCK * RPT;   // 1024

__global__ __launch_bounds__(BLOCK) void LIFSpike_kernel(
    const fx4* __restrict__ x, fx4* __restrict__ out) {
    const int nb = gridDim.x;
    const int b = blockIdx.x;
    // bijective XCD swizzle (nb divisible by 8): XCD i gets blocks with b%8==i,
    // remapped so each XCD's blocks cover one contiguous slab of memory.
    const int chunk = (b & 7) * (nb >> 3) + (b >> 3);
    const size_t row0 = (size_t)chunk * ROWS_PER_BLOCK + threadIdx.x;

    fx4 cur[QPR], nxt[QPR];
    const fx4* p0 = x + row0 * QPR;
#pragma unroll
    for (int j = 0; j < QPR; ++j) cur[j] = p0[j];

#pragma unroll
    for (int k = 0; k < RPT; ++k) {
        // Prefetch next row before the serial scan of the current row.
        if (k + 1 < RPT) {
            const fx4* pn = x + (row0 + (size_t)(k + 1) * BLOCK) * QPR;
#pragma unroll
            for (int j = 0; j < QPR; ++j) nxt[j] = pn[j];
        }

        fx4* po = out + (row0 + (size_t)k * BLOCK) * QPR;
        float u = 0.0f, o = 0.0f;
#pragma unroll
        for (int j = 0; j < QPR; ++j) {
            fx4 v = cur[j];
            fx4 r;
            u = TAU * u * (1.0f - o) + v.x;
            o = (u > VTH) ? 1.0f : 0.0f;
            r.x = o;
            u = TAU * u * (1.0f - o) + v.y;
            o = (u > VTH) ? 1.0f : 0.0f;
            r.y = o;
            u = TAU * u * (1.0f - o) + v.z;
            o = (u > VTH) ? 1.0f : 0.0f;
            r.z = o;
            u = TAU * u * (1.0f - o) + v.w;
            o = (u > VTH) ? 1.0f : 0.0f;
            r.w = o;
            __builtin_nontemporal_store(r, po + j);
        }

#pragma unroll
        for (int j = 0; j < QPR; ++j) cur[j] = nxt[j];
    }
}

extern "C" void kernel_launch(void* const* d_in, const int* in_sizes, int n_in,
                              void* d_out, int out_size, void* d_ws, size_t ws_size,
                              hipStream_t stream) {
    const fx4* x = (const fx4*)d_in[0];
    fx4* out = (fx4*)d_out;
    int n_rows = in_sizes[0] / T;                 // 1,048,576
    int grid = n_rows / ROWS_PER_BLOCK;           // 1024 blocks (exact)
    LIFSpike_kernel<<<grid, BLOCK, 0, stream>>>(x, out);
}

// Round 5
// 389.372 us; speedup vs baseline: 1.3684x; 1.3684x over previous
//
#include <hip/hip_runtime.h>

// LIF spike scan: x[N, T=32] fp32, scan over contiguous T axis.
//   u = 0.25*u*(1-o_prev) + x_t ;  o = (u > 0.5) ? 1 : 0
// 0.25*u exact (pow2), (1-o) in {0,1} exact -> bit-exact vs numpy fp32 ref.
//
// R5: keep the read stream continuously in flight.
//  - each block: 4 tiles of 256 rows x 32 steps (32 KB LDS, reused).
//  - register prefetch of tile k+1 issued BEFORE scanning tile k; its
//    latency is absorbed by the scan+stores; LDS write happens after.
//  - loads fully coalesced (lane-consecutive float4).
//  - LDS row reads rotated by lane ((j+t)&7): spreads 64 lanes over all
//    32 banks (plain row-major would put every lane on banks 0-3).
//  - stores straight from registers, 16B/lane: R1 proved L2 merges these
//    to ideal WRITE_SIZE (133 MB). No nontemporal (R4 disaster: 368 MB).

constexpr int T = 32;
constexpr float TAU = 0.25f;
constexpr float VTH = 0.5f;
constexpr int QPR = T / 4;              // 8 float4 per row
constexpr int BLOCK = 256;
constexpr int TILE_F4 = BLOCK * QPR;    // 2048 float4 = 32 KB
constexpr int TPB = 4;                  // tiles per block

__global__ __launch_bounds__(BLOCK) void LIFSpike_kernel(
    const float4* __restrict__ x, float4* __restrict__ out) {
    __shared__ float4 tile[TILE_F4];

    const int t = threadIdx.x;
    const size_t base = (size_t)blockIdx.x * TPB * TILE_F4;  // float4 units
    const float4* __restrict__ xq = x + base;
    float4* __restrict__ oq = out + base;

    float4 pf[QPR];

    // Prologue: load tile 0 (coalesced) and stage to LDS.
#pragma unroll
    for (int j = 0; j < QPR; ++j) pf[j] = xq[j * BLOCK + t];
#pragma unroll
    for (int j = 0; j < QPR; ++j) tile[j * BLOCK + t] = pf[j];
    __syncthreads();

    for (int k = 0; k < TPB; ++k) {
        // Issue prefetch of tile k+1 first; scan+stores absorb its latency.
        if (k + 1 < TPB) {
#pragma unroll
            for (int j = 0; j < QPR; ++j)
                pf[j] = xq[(size_t)(k + 1) * TILE_F4 + j * BLOCK + t];
        }

        // Read own row from LDS with per-lane rotation (bank-conflict-free).
        float4 v[QPR];
#pragma unroll
        for (int j = 0; j < QPR; ++j) {
            int jj = (j + t) & 7;
            v[jj] = tile[t * QPR + jj];
        }

        // Serial LIF scan over the 32 steps.
        float u = 0.0f, o = 0.0f;
        float4 r[QPR];
#pragma unroll
        for (int j = 0; j < QPR; ++j) {
            u = TAU * u * (1.0f - o) + v[j].x;
            o = (u > VTH) ? 1.0f : 0.0f;
            r[j].x = o;
            u = TAU * u * (1.0f - o) + v[j].y;
            o = (u > VTH) ? 1.0f : 0.0f;
            r[j].y = o;
            u = TAU * u * (1.0f - o) + v[j].z;
            o = (u > VTH) ? 1.0f : 0.0f;
            r[j].z = o;
            u = TAU * u * (1.0f - o) + v[j].w;
            o = (u > VTH) ? 1.0f : 0.0f;
            r[j].w = o;
        }

        // Store own row (16B/lane, merged to full lines in L2).
#pragma unroll
        for (int j = 0; j < QPR; ++j)
            oq[(size_t)k * TILE_F4 + t * QPR + j] = r[j];

        __syncthreads();  // everyone done reading tile k
        if (k + 1 < TPB) {
#pragma unroll
            for (int j = 0; j < QPR; ++j) tile[j * BLOCK + t] = pf[j];
            __syncthreads();  // tile k+1 visible
        }
    }
}

extern "C" void kernel_launch(void* const* d_in, const int* in_sizes, int n_in,
                              void* d_out, int out_size, void* d_ws, size_t ws_size,
                              hipStream_t stream) {
    const float4* x = (const float4*)d_in[0];
    float4* out = (float4*)d_out;
    int n_rows = in_sizes[0] / T;                   // 1,048,576
    int grid = n_rows / (BLOCK * TPB);              // 1024 blocks (exact)
    LIFSpike_kernel<<<grid, BLOCK, 0, stream>>>(x, out);
}

// Round 6
// 245.785 us; speedup vs baseline: 2.1679x; 1.5842x over previous
//
#include <hip/hip_runtime.h>

// LIF spike scan: x[N, T=32] fp32, scan over contiguous T axis.
//   u = 0.25*u*(1-o_prev) + x_t ;  o = (u > 0.5) ? 1 : 0
// 0.25*u exact (pow2), (1-o) in {0,1} exact -> bit-exact vs numpy fp32 ref.
//
// R6: REAL software pipeline.
//  Evidence: R4's VGPR=36 proves the compiler sank the prefetch loads past
//  the scan (cur+nxt need 64 VGPRs) -> no round so far actually pipelined,
//  and all plateau at ~2.5 TB/s = (memory-demand duty ~40%) x 6.3 TB/s.
//  Fix: sched_barrier(0) fences so loads for row k+1 are ISSUED before the
//  serial scan of row k; scan+stores hide the load latency; every wave has
//  8 KB of loads outstanding almost continuously.
//  Stores: plain 16B per-lane row stores, interleaved with the scan
//  (R1-proven: L2 merges to ideal WRITE_SIZE ~133 MB; nontemporal was the
//  R4 disaster, burst-at-end was the R5 disaster).

constexpr int T = 32;
constexpr float TAU = 0.25f;
constexpr float VTH = 0.5f;
constexpr int QPR = T / 4;                    // 8 float4 per row
constexpr int RPT = 4;                        // rows per thread
constexpr int BLOCK = 256;
constexpr int ROWS_PER_BLOCK = BLOCK * RPT;   // 1024

__global__ __launch_bounds__(BLOCK) void LIFSpike_kernel(
    const float4* __restrict__ x, float4* __restrict__ out) {
    const size_t row0 = (size_t)blockIdx.x * ROWS_PER_BLOCK + threadIdx.x;

    float4 cur[QPR], nxt[QPR];
    const float4* p0 = x + row0 * QPR;
#pragma unroll
    for (int j = 0; j < QPR; ++j) cur[j] = p0[j];

#pragma unroll
    for (int k = 0; k < RPT; ++k) {
        // Issue prefetch of row k+1 FIRST...
        if (k + 1 < RPT) {
            const float4* pn = x + (row0 + (size_t)(k + 1) * BLOCK) * QPR;
#pragma unroll
            for (int j = 0; j < QPR; ++j) nxt[j] = pn[j];
        }
        // ...and forbid the scheduler from sinking those loads below here.
        __builtin_amdgcn_sched_barrier(0);

        float4* po = out + (row0 + (size_t)k * BLOCK) * QPR;
        float u = 0.0f, o = 0.0f;
#pragma unroll
        for (int j = 0; j < QPR; ++j) {
            float4 v = cur[j];
            float4 r;
            u = TAU * u * (1.0f - o) + v.x;
            o = (u > VTH) ? 1.0f : 0.0f;
            r.x = o;
            u = TAU * u * (1.0f - o) + v.y;
            o = (u > VTH) ? 1.0f : 0.0f;
            r.y = o;
            u = TAU * u * (1.0f - o) + v.z;
            o = (u > VTH) ? 1.0f : 0.0f;
            r.z = o;
            u = TAU * u * (1.0f - o) + v.w;
            o = (u > VTH) ? 1.0f : 0.0f;
            r.w = o;
            po[j] = r;  // interleaved store: spreads write demand
        }
        __builtin_amdgcn_sched_barrier(0);

#pragma unroll
        for (int j = 0; j < QPR; ++j) cur[j] = nxt[j];
    }
}

extern "C" void kernel_launch(void* const* d_in, const int* in_sizes, int n_in,
                              void* d_out, int out_size, void* d_ws, size_t ws_size,
                              hipStream_t stream) {
    const float4* x = (const float4*)d_in[0];
    float4* out = (float4*)d_out;
    int n_rows = in_sizes[0] / T;                 // 1,048,576
    int grid = n_rows / ROWS_PER_BLOCK;           // 1024 blocks (exact)
    LIFSpike_kernel<<<grid, BLOCK, 0, stream>>>(x, out);
}